// Round 22
// baseline (875.814 us; speedup 1.0000x reference)
//
#include <hip/hip_runtime.h>
#include <hip/hip_bf16.h>
#include <stdint.h>

#define T_N 8192
#define K_N 1024
#define D_N 1024
#define LMBDA 5.0f
#define BIGF 3.0e38f
#define CMAX 16
#define THR 26.0f      // 2*lambda + 4 bound + >10 ulp slack (r9-validated)
#define QNAN 0x7FC00000

// ---------------- norms: numpy-pairwise-exact sum of squares per row ----------------
__global__ __launch_bounds__(256) void k_norms(const float* __restrict__ F,
                                               const float* __restrict__ C,
                                               float* __restrict__ sf2,
                                               float* __restrict__ sc2) {
#pragma clang fp contract(off)
  int wave = threadIdx.x >> 6;
  int lane = threadIdx.x & 63;
  int row = blockIdx.x * 4 + wave;
  const float* src;
  float* dst;
  if (row < T_N) { src = F + (size_t)row * D_N; dst = sf2 + row; }
  else           { src = C + (size_t)(row - T_N) * D_N; dst = sc2 + (row - T_N); }
  int leaf = lane >> 3, j = lane & 7;
  const float* p = src + leaf * 128 + j;
  float x = p[0];
  float r = x * x;
#pragma unroll
  for (int i = 1; i < 16; ++i) {
    float y = p[8 * i];
    r = r + y * y;
  }
  r = r + __shfl_xor(r, 1, 64);
  r = r + __shfl_xor(r, 2, 64);
  r = r + __shfl_xor(r, 4, 64);
  r = r + __shfl_xor(r, 8, 64);
  r = r + __shfl_xor(r, 16, 64);
  r = r + __shfl_xor(r, 32, 64);
  if (lane == 0) *dst = r;
}

// ---------------- d2 GEMM: OpenBLAS-faithful f32, 64x128 tile / 4x8 microtile (r19/r20) -----
__global__ __launch_bounds__(256) void k_gemm(const float* __restrict__ F,
                                              const float* __restrict__ C,
                                              const float* __restrict__ sf2,
                                              const float* __restrict__ sc2,
                                              float* __restrict__ d2) {
  __shared__ float As[32][68];    // [d][t]
  __shared__ float Bs[32][132];   // [d][k]
  int t0 = (int)(blockIdx.x >> 3) * 64;
  int k0 = (int)(blockIdx.x & 7) * 128;
  int tid = threadIdx.x;
  int tx = tid & 15, ty = tid >> 4;
  float dot[4][8], acc[4][8];
#pragma unroll
  for (int i = 0; i < 4; ++i)
#pragma unroll
    for (int j = 0; j < 8; ++j) { dot[i][j] = 0.0f; acc[i][j] = 0.0f; }
  int ra = tid & 63, ca = (tid >> 6) * 8;
  int rb = tid & 127, cb = (tid >> 7) * 16;
  for (int d0 = 0; d0 < D_N; d0 += 32) {
    __syncthreads();
    {
      const float* fa = &F[(size_t)(t0 + ra) * D_N + d0 + ca];
      float4 a0 = *(const float4*)fa;
      float4 a1 = *(const float4*)(fa + 4);
      As[ca + 0][ra] = a0.x; As[ca + 1][ra] = a0.y; As[ca + 2][ra] = a0.z; As[ca + 3][ra] = a0.w;
      As[ca + 4][ra] = a1.x; As[ca + 5][ra] = a1.y; As[ca + 6][ra] = a1.z; As[ca + 7][ra] = a1.w;
      const float* fb = &C[(size_t)(k0 + rb) * D_N + d0 + cb];
      float4 b0 = *(const float4*)fb;
      float4 b1 = *(const float4*)(fb + 4);
      float4 b2 = *(const float4*)(fb + 8);
      float4 b3 = *(const float4*)(fb + 12);
      Bs[cb + 0][rb] = b0.x; Bs[cb + 1][rb] = b0.y; Bs[cb + 2][rb] = b0.z; Bs[cb + 3][rb] = b0.w;
      Bs[cb + 4][rb] = b1.x; Bs[cb + 5][rb] = b1.y; Bs[cb + 6][rb] = b1.z; Bs[cb + 7][rb] = b1.w;
      Bs[cb + 8][rb] = b2.x; Bs[cb + 9][rb] = b2.y; Bs[cb + 10][rb] = b2.z; Bs[cb + 11][rb] = b2.w;
      Bs[cb + 12][rb] = b3.x; Bs[cb + 13][rb] = b3.y; Bs[cb + 14][rb] = b3.z; Bs[cb + 15][rb] = b3.w;
    }
    __syncthreads();
#pragma unroll
    for (int d = 0; d < 32; ++d) {
      float4 a = *(const float4*)&As[d][ty * 4];
      float4 b0 = *(const float4*)&Bs[d][tx * 4];
      float4 b1 = *(const float4*)&Bs[d][64 + tx * 4];
      float av[4] = {a.x, a.y, a.z, a.w};
      float bv[8] = {b0.x, b0.y, b0.z, b0.w, b1.x, b1.y, b1.z, b1.w};
#pragma unroll
      for (int i = 0; i < 4; ++i)
#pragma unroll
        for (int j = 0; j < 8; ++j)
          acc[i][j] = fmaf(av[i], bv[j], acc[i][j]);
    }
    if (d0 == 352) {
#pragma unroll
      for (int i = 0; i < 4; ++i)
#pragma unroll
        for (int j = 0; j < 8; ++j) { dot[i][j] = acc[i][j]; acc[i][j] = 0.0f; }
    }
    if (d0 == 736) {
#pragma unroll
      for (int i = 0; i < 4; ++i)
#pragma unroll
        for (int j = 0; j < 8; ++j) { dot[i][j] = dot[i][j] + acc[i][j]; acc[i][j] = 0.0f; }
    }
  }
  {
#pragma clang fp contract(off)
#pragma unroll
    for (int i = 0; i < 4; ++i) {
      int t = t0 + ty * 4 + i;
      float sa = sf2[t];
      float o[8];
#pragma unroll
      for (int j = 0; j < 4; ++j) {
        float dsum = dot[i][j] + acc[i][j];
        float two = 2.0f * dsum;
        o[j] = (sa - two) + sc2[k0 + tx * 4 + j];
      }
#pragma unroll
      for (int j = 4; j < 8; ++j) {
        float dsum = dot[i][j] + acc[i][j];
        float two = 2.0f * dsum;
        o[j] = (sa - two) + sc2[k0 + 64 + tx * 4 + (j - 4)];
      }
      float4 o0; o0.x = o[0]; o0.y = o[1]; o0.z = o[2]; o0.w = o[3];
      float4 o1; o1.x = o[4]; o1.y = o[5]; o1.z = o[6]; o1.w = o[7];
      float* dp = &d2[(size_t)t * K_N + k0 + tx * 4];
      *(float4*)dp = o0;
      *(float4*)(dp + 64) = o1;
    }
  }
}

// ---------------- cand: per row, candidate list {k: d <= dmin+THR} + row dmin (CMAX=16) -----
__global__ __launch_bounds__(256) void k_cand(const float* __restrict__ d2,
                                              int2* __restrict__ cand,
                                              float* __restrict__ dminOut) {
  int wave = threadIdx.x >> 6;
  int lane = threadIdx.x & 63;
  int row = blockIdx.x * 4 + wave;
  const float4* p = (const float4*)(d2 + (size_t)row * K_N + lane * 16);
  float4 v0 = p[0], v1 = p[1], v2 = p[2], v3 = p[3];
  float m = fminf(fminf(fminf(v0.x, v0.y), fminf(v0.z, v0.w)),
                  fminf(fminf(v1.x, v1.y), fminf(v1.z, v1.w)));
  float n = fminf(fminf(fminf(v2.x, v2.y), fminf(v2.z, v2.w)),
                  fminf(fminf(v3.x, v3.y), fminf(v3.z, v3.w)));
  m = fminf(m, n);
  m = fminf(m, __shfl_xor(m, 1, 64));
  m = fminf(m, __shfl_xor(m, 2, 64));
  m = fminf(m, __shfl_xor(m, 4, 64));
  m = fminf(m, __shfl_xor(m, 8, 64));
  m = fminf(m, __shfl_xor(m, 16, 64));
  m = fminf(m, __shfl_xor(m, 32, 64));
  if (lane == 0) dminOut[row] = m;
  float thr = m + THR;
  unsigned flags = 0;
#define TESTC(J, VAL) if ((VAL) <= thr) flags |= (1u << (J));
  TESTC(0, v0.x) TESTC(1, v0.y) TESTC(2, v0.z) TESTC(3, v0.w)
  TESTC(4, v1.x) TESTC(5, v1.y) TESTC(6, v1.z) TESTC(7, v1.w)
  TESTC(8, v2.x) TESTC(9, v2.y) TESTC(10, v2.z) TESTC(11, v2.w)
  TESTC(12, v3.x) TESTC(13, v3.y) TESTC(14, v3.z) TESTC(15, v3.w)
#undef TESTC
  int c = __popc(flags);
  int pre = c;
#pragma unroll
  for (int off = 1; off <= 32; off <<= 1) {
    int t = __shfl_up(pre, off, 64);
    if (lane >= off) pre += t;
  }
  int idx = pre - c;
  int2* rowp = cand + (size_t)row * CMAX;
  int kb = lane * 16;
#define EMITC(J, VAL)                                                        \
  if (flags & (1u << (J))) {                                                 \
    if (idx < CMAX) rowp[idx] = make_int2(kb + (J), __float_as_int(VAL));    \
    ++idx;                                                                   \
  }
  EMITC(0, v0.x) EMITC(1, v0.y) EMITC(2, v0.z) EMITC(3, v0.w)
  EMITC(4, v1.x) EMITC(5, v1.y) EMITC(6, v1.z) EMITC(7, v1.w)
  EMITC(8, v2.x) EMITC(9, v2.y) EMITC(10, v2.z) EMITC(11, v2.w)
  EMITC(12, v3.x) EMITC(13, v3.y) EMITC(14, v3.z) EMITC(15, v3.w)
#undef EMITC
}

// ---------------- prev4: per-group (4 rows x 16 slots) lane statics ----------------
// Lane L (s=L&15): quadrant q = 3-(L>>4) -> row 4g+q. Statics for its k:
//   pp  = byteaddr of k in S_{4g-1} (prev t3') list; pe1/pe2/pe3 = d of k in rows
//   4g-3 / 4g-2 / 4g-1 (prev t1', t2', t3'); d0s/d1s/d2s = d of k in rows 4g..4g+2;
//   dOwn = own-row d. Absent lookups = NaN (validated chain-death).
__global__ __launch_bounds__(256) void k_prev4(const int2* __restrict__ cand,
                                               int4* __restrict__ pb1,
                                               int4* __restrict__ pb2) {
  __shared__ int2 rows[4][7][16];   // [wave][4g-3 .. 4g+3][slot]
  int w = threadIdx.x >> 6, lane = threadIdx.x & 63;
  int g = blockIdx.x * 4 + w;
  int base = 4 * g - 3;
  for (int i = lane; i < 112; i += 64) {
    int rr = i >> 4, ss = i & 15;
    int trow = base + rr;
    rows[w][rr][ss] = (trow >= 0) ? cand[(size_t)trow * CMAX + ss] : make_int2(-2, 0);
  }
  __syncthreads();
  int q = 3 - (lane >> 4);
  int s = lane & 15;
  int2 me = rows[w][3 + q][s];
  int k = me.x;
  int pp = -4;
  int pe1 = QNAN, pe2 = QNAN, pe3 = QNAN;
  int d0s = QNAN, d1s = QNAN, d2s = QNAN;
#pragma unroll
  for (int i = 0; i < 16; ++i) {
    if (rows[w][0][i].x == k) pe1 = rows[w][0][i].y;
    if (rows[w][1][i].x == k) pe2 = rows[w][1][i].y;
    if (rows[w][2][i].x == k) { pp = i * 4; pe3 = rows[w][2][i].y; }
    if (rows[w][3][i].x == k) d0s = rows[w][3][i].y;
    if (rows[w][4][i].x == k) d1s = rows[w][4][i].y;
    if (rows[w][5][i].x == k) d2s = rows[w][5][i].y;
  }
  if (k < 0) pp = -4;
  pb1[(size_t)g * 64 + lane] = make_int4(pp, me.y, d0s, d1s);
  pb2[(size_t)g * 64 + lane] = make_int4(d2s, pe3, pe1, pe2);
}

// ---------------- DPP min within each 16-lane row (result at lanes 15/31/47/63) -------------
__device__ __forceinline__ float dpp_min16(float x) {
  int t;
  t = __builtin_amdgcn_update_dpp(__float_as_int(x), __float_as_int(x), 0x111, 0xF, 0xF, false);
  x = fminf(x, __int_as_float(t));
  t = __builtin_amdgcn_update_dpp(__float_as_int(x), __float_as_int(x), 0x112, 0xF, 0xF, false);
  x = fminf(x, __int_as_float(t));
  t = __builtin_amdgcn_update_dpp(__float_as_int(x), __float_as_int(x), 0x114, 0xF, 0xF, false);
  x = fminf(x, __int_as_float(t));
  t = __builtin_amdgcn_update_dpp(__float_as_int(x), __float_as_int(x), 0x118, 0xF, 0xF, false);
  x = fminf(x, __int_as_float(t));
  return x;
}
__device__ __forceinline__ float rdlane(float x, int l) {
  return __int_as_float(__builtin_amdgcn_readlane(__float_as_int(x), l));
}

// ---------------- pass1: G=4 sparse chain — payload is min(A3,B3); C/D/E injected -----------
// fp = f_{4g-1}[k] = min( gather(xAB_prev), C3(pe*,a0c), D3(pe*,a1c), E3(pe3,at2p) )
//   [gathered-statics injection; all terms bit-exact replays of the prev group's walks]
// A-walk (boundary) / B-walk (from ain) depth 0..3; xAB = payload (early, off alpha tail).
// red1 -> a_t0, a_t1 (dmin trick); red2 folds Cterm/Dterm (alpha path only, pipelined).
__global__ __launch_bounds__(64, 1) void k_pass1(const int4* __restrict__ pb1,
                                                 const int4* __restrict__ pb2,
                                                 const float* __restrict__ dminArr,
                                                 float* __restrict__ alphaOut) {
  const int lane = threadIdx.x;
  const int q = 3 - (lane >> 4);
  const int4* b1p = pb1 + lane;
  const int4* b2p = pb2 + lane;
  int4 r1[4], r2[4];
#pragma unroll
  for (int u = 0; u < 4; ++u) {
    r1[u] = b1p[(size_t)u * 64];
    r2[u] = b2p[(size_t)u * 64];
  }
  float pay = 0.0f;         // group 0: pp=-4, value irrelevant
  float red2c = BIGF;       // -> a_{-2..-1} = 0 at iter 0
  float dm2c = 0.0f, dm3c = 0.0f, a1c = 0.0f, a0c = 0.0f;
  float areg = 0.0f;
  const int NG = T_N / 4;
  float dmv = dminArr[lane];
  float dmv_next;
  for (int gb = 0; gb < NG; gb += 16) {
    int nb = gb + 16; if (nb >= NG) nb = 0;
    dmv_next = dminArr[nb * 4 + lane];
    for (int g4 = 0; g4 < 16; g4 += 4) {
#pragma unroll
      for (int u = 0; u < 4; ++u) {
        int g = gb + g4 + u;
        int4 pa = r1[u];
        int4 pb = r2[u];
        // the group's single gather (payload = xAB of prev iteration, ready early)
        int g1 = __builtin_amdgcn_ds_bpermute(pa.x, __float_as_int(pay));
        // prefetch group g+4
        int gn = g + 4; if (gn > NG - 1) gn = NG - 1;
        r1[u] = b1p[(size_t)gn * 64];
        r2[u] = b2p[(size_t)gn * 64];
        // finalize a_{4g-2}, a_{4g-1} from carried red2 (off gather path)
        float at2p = fminf(rdlane(red2c, 31), dm2c + a1c);
        float ain = fminf(rdlane(red2c, 15), dm3c + at2p);
        int posB = 4 * g - 1;
        if (posB >= 0) {
          areg = (((posB - 1) & 63) == lane) ? at2p : areg;
          areg = ((posB & 63) == lane) ? ain : areg;
          if ((posB & 63) == 63) alphaOut[(posB & ~63) + lane] = areg;
        }
        int r0 = 4 * (g4 + u);
        float dm0 = rdlane(dmv, r0);
        float dm1 = rdlane(dmv, r0 + 1);
        float dm2 = rdlane(dmv, r0 + 2);
        float dm3 = rdlane(dmv, r0 + 3);
        // C/D/E injections from gathered statics (computed during gather latency)
        float pe1 = __int_as_float(pb.z);
        float pe2 = __int_as_float(pb.w);
        float pe3 = __int_as_float(pb.y);
        float Cw1 = pe1 + a0c;
        float Cw2 = pe2 + (Cw1 - LMBDA);
        float c3r = pe3 + (Cw2 - LMBDA);
        float Dw2 = pe2 + a1c;
        float d3r = pe3 + (Dw2 - LMBDA);
        float injE = pe3 + at2p;
        float inj = fminf(fminf(c3r, d3r), injE);   // NaN terms drop (minNum)
        // fp (payload-gather + injections)
        float fp = (pa.x < 0) ? BIGF : fminf(__int_as_float(g1), inj);
        // A/B walks
        float dOwn = __int_as_float(pa.y);
        float d0s = __int_as_float(pa.z);
        float d1s = __int_as_float(pa.w);
        float d2s = __int_as_float(pb.x);
        float A0 = d0s + (fp - LMBDA);
        float A1 = d1s + (A0 - LMBDA);
        float A2 = d2s + (A1 - LMBDA);
        float A3 = dOwn + (A2 - LMBDA);
        float B0 = d0s + ain;
        float B1 = d1s + (B0 - LMBDA);
        float B2 = d2s + (B1 - LMBDA);
        float B3 = dOwn + (B2 - LMBDA);
        float xA = (q == 0) ? A0 : (q == 1) ? A1 : (q == 2) ? A2 : A3;
        float xB = (q == 0) ? B0 : (q == 1) ? B1 : (q == 2) ? B2 : B3;
        float xAB = fminf(xA, xB);
        pay = xAB;                                   // payload for next gather (EARLY)
        // alpha tail (off payload cycle)
        float red1 = dpp_min16(xAB);
        float a0 = rdlane(red1, 63);
        float a1 = fminf(rdlane(red1, 47), dm1 + a0);
        areg = (((4 * g) & 63) == lane) ? a0 : areg;
        areg = (((4 * g + 1) & 63) == lane) ? a1 : areg;
        float cw1 = d1s + a0;
        float cw2 = d2s + (cw1 - LMBDA);
        float Cin = (q == 2) ? cw1 : cw2;
        float Cterm = dOwn + (Cin - LMBDA);
        float Dterm = dOwn + ((d2s + a1) - LMBDA);
        Dterm = (q == 3) ? Dterm : __int_as_float(QNAN);
        float xr = fminf(fminf(xAB, Cterm), Dterm);
        red2c = dpp_min16(xr);
        dm2c = dm2; dm3c = dm3; a1c = a1; a0c = a0;
      }
    }
    dmv = dmv_next;
  }
  // epilogue: a_{8190}, a_{8191}
  float at2 = fminf(rdlane(red2c, 31), dm2c + a1c);
  float at3 = fminf(rdlane(red2c, 15), dm3c + at2);
  areg = ((8190 & 63) == lane) ? at2 : areg;
  areg = ((8191 & 63) == lane) ? at3 : areg;
  alphaOut[(T_N - 64) + lane] = areg;
}

// ---------------- pass2: chunked warm-start replay per k (WARM=64 validated; CH=128) --------
#define CH 128
#define WARM 64
__global__ __launch_bounds__(256) void k_pass2(const float* __restrict__ d2,
                                               const float* __restrict__ AOUT,
                                               unsigned* __restrict__ pack) {
  int kb = blockIdx.x & 3;
  int tc = blockIdx.x >> 2;
  int k = kb * 256 + threadIdx.x;
  int ts = tc * CH;
  int start = ts - WARM; if (start < 0) start = 0;
  int end = ts + CH;
  __shared__ float lal[CH + WARM + 1];
  for (int i = threadIdx.x; i < end - start + 1; i += 256) {
    int idx = start - 1 + i;
    lal[i] = (idx < 0) ? 0.0f : AOUT[idx];
  }
  __syncthreads();
  float f = BIGF;
  unsigned s = 0;
#pragma unroll 4
  for (int tau = start; tau < end; ++tau) {
    float a_in = lal[tau - start];
    float d = d2[(size_t)tau * K_N + k];
    float ext = f - LMBDA;
    if (a_in < ext) s = (unsigned)tau;
    f = d + fminf(a_in, ext);
    if (tau >= ts) {
      float a_out = lal[tau - start + 1];
      if (f == a_out) atomicMin(&pack[tau], ((unsigned)k << 13) | s);
    }
  }
}

// ---------------- backtrack: ballot run-skip serial chase + parallel fill (validated r1) ----------------
__global__ __launch_bounds__(256) void k_backtrack(const unsigned* __restrict__ pack,
                                                   unsigned* __restrict__ unitsWs,
                                                   float* __restrict__ outUnits) {
  __shared__ unsigned lp[T_N];
  __shared__ unsigned long long msk[T_N / 64];
  int tid = threadIdx.x;
  for (int i = tid * 4; i < T_N; i += 1024) {
    *(uint4*)&lp[i] = *(const uint4*)&pack[i];
  }
  __syncthreads();
  if (tid < 64) {
    int lane = tid;
    int cur = T_N;
    for (int B = T_N - 64; B >= 0; B -= 64) {
      unsigned long long marks = 0ull;
      if (cur > B) {
        unsigned pk = lp[B + lane];
        int bv = (int)(pk & 8191u);
        unsigned long long run = __ballot(bv == B + lane);
        while (cur > B) {
          int L = cur - 1 - B;
          unsigned long long below = (L == 63) ? ~0ull : ((1ull << (L + 1)) - 1ull);
          unsigned long long nz = (~run) & below;
          if (nz == 0ull) { marks |= below; cur = B; break; }
          int j = 63 - __builtin_clzll(nz);
          marks |= below & ~((1ull << j) - 1ull);
          int nb = __builtin_amdgcn_readlane(bv, j);
          cur = nb;
          if (cur > B + j) cur = B + j;
        }
      }
      if (lane == 0) msk[B >> 6] = marks;
    }
  }
  __syncthreads();
  for (int p = tid; p < T_N; p += 256) {
    int w = p >> 6;
    unsigned long long m = msk[w] & (~0ull << (p & 63));
    while (m == 0ull) { ++w; m = msk[w]; }
    int idx = (w << 6) + (int)__builtin_ctzll(m);
    unsigned g = (lp[idx] >> 13) & 1023u;
    unitsWs[p] = g;
    outUnits[p] = (float)g;
  }
}

// ---------------- gather: quantized[t] = codebook[units[t]] ----------------
__global__ __launch_bounds__(256) void k_gather(const float* __restrict__ C,
                                                const unsigned* __restrict__ unitsWs,
                                                float* __restrict__ out) {
  int t = blockIdx.x;
  unsigned u = unitsWs[t] & 1023u;
  const float4* src = (const float4*)(C + (size_t)u * D_N);
  float4* dst = (float4*)(out + (size_t)t * D_N);
  dst[threadIdx.x] = src[threadIdx.x];
}

extern "C" void kernel_launch(void* const* d_in, const int* in_sizes, int n_in,
                              void* d_out, int out_size, void* d_ws, size_t ws_size,
                              hipStream_t stream) {
  const float* F = (const float*)d_in[0];
  const float* C = (const float*)d_in[1];
  float* out = (float*)d_out;
  float* d2 = out;                                  // reuse quantized region as d2 scratch
  float* outUnits = out + (size_t)T_N * D_N;
  char* ws = (char*)d_ws;
  float* alphaOut = (float*)(ws);                    // 32 KB
  unsigned* pack = (unsigned*)(ws + (32 << 10));     // 32 KB
  unsigned* unitsWs = (unsigned*)(ws + (64 << 10));  // 32 KB
  float* sf2 = (float*)(ws + (96 << 10));            // 32 KB
  float* sc2 = (float*)(ws + (128 << 10));           // 4 KB
  float* dminArr = (float*)(ws + (160 << 10));       // 32 KB
  int2* cand = (int2*)(ws + (1 << 20));              // 1 MB (8192 x 16 x 8B)
  int4* pb1 = (int4*)(ws + (3 << 20));               // 2 MB (2048 x 64 x 16B)
  int4* pb2 = (int4*)(ws + (5 << 20));               // 2 MB

  k_norms<<<(T_N + K_N) / 4, 256, 0, stream>>>(F, C, sf2, sc2);
  hipMemsetAsync(pack, 0xFF, T_N * sizeof(unsigned), stream);
  hipMemsetAsync(cand, 0xFF, (size_t)T_N * CMAX * sizeof(int2), stream);
  k_gemm<<<(T_N / 64) * (K_N / 128), 256, 0, stream>>>(F, C, sf2, sc2, d2);
  k_cand<<<T_N / 4, 256, 0, stream>>>(d2, cand, dminArr);
  k_prev4<<<(T_N / 4) / 4, 256, 0, stream>>>(cand, pb1, pb2);
  k_pass1<<<1, 64, 0, stream>>>(pb1, pb2, dminArr, alphaOut);
  k_pass2<<<(T_N / CH) * 4, 256, 0, stream>>>(d2, alphaOut, pack);
  k_backtrack<<<1, 256, 0, stream>>>(pack, unitsWs, outUnits);
  k_gather<<<T_N, 256, 0, stream>>>(C, unitsWs, out);
}

// Round 23
// 846.931 us; speedup vs baseline: 1.0341x; 1.0341x over previous
//
#include <hip/hip_runtime.h>
#include <hip/hip_bf16.h>
#include <stdint.h>

#define T_N 8192
#define K_N 1024
#define D_N 1024
#define LMBDA 5.0f
#define BIGF 3.0e38f
#define CMAX 16
#define THR 26.0f      // 2*lambda + 4 bound + >10 ulp slack (r9-validated)
#define QNAN 0x7FC00000

// ---------------- norms: numpy-pairwise-exact sum of squares per row ----------------
__global__ __launch_bounds__(256) void k_norms(const float* __restrict__ F,
                                               const float* __restrict__ C,
                                               float* __restrict__ sf2,
                                               float* __restrict__ sc2) {
#pragma clang fp contract(off)
  int wave = threadIdx.x >> 6;
  int lane = threadIdx.x & 63;
  int row = blockIdx.x * 4 + wave;
  const float* src;
  float* dst;
  if (row < T_N) { src = F + (size_t)row * D_N; dst = sf2 + row; }
  else           { src = C + (size_t)(row - T_N) * D_N; dst = sc2 + (row - T_N); }
  int leaf = lane >> 3, j = lane & 7;
  const float* p = src + leaf * 128 + j;
  float x = p[0];
  float r = x * x;
#pragma unroll
  for (int i = 1; i < 16; ++i) {
    float y = p[8 * i];
    r = r + y * y;
  }
  r = r + __shfl_xor(r, 1, 64);
  r = r + __shfl_xor(r, 2, 64);
  r = r + __shfl_xor(r, 4, 64);
  r = r + __shfl_xor(r, 8, 64);
  r = r + __shfl_xor(r, 16, 64);
  r = r + __shfl_xor(r, 32, 64);
  if (lane == 0) *dst = r;
}

// ---------------- d2 GEMM: OpenBLAS-faithful f32, 64x128 tile / 4x8 microtile (r19/r20) -----
__global__ __launch_bounds__(256) void k_gemm(const float* __restrict__ F,
                                              const float* __restrict__ C,
                                              const float* __restrict__ sf2,
                                              const float* __restrict__ sc2,
                                              float* __restrict__ d2) {
  __shared__ float As[32][68];    // [d][t]
  __shared__ float Bs[32][132];   // [d][k]
  int t0 = (int)(blockIdx.x >> 3) * 64;
  int k0 = (int)(blockIdx.x & 7) * 128;
  int tid = threadIdx.x;
  int tx = tid & 15, ty = tid >> 4;
  float dot[4][8], acc[4][8];
#pragma unroll
  for (int i = 0; i < 4; ++i)
#pragma unroll
    for (int j = 0; j < 8; ++j) { dot[i][j] = 0.0f; acc[i][j] = 0.0f; }
  int ra = tid & 63, ca = (tid >> 6) * 8;
  int rb = tid & 127, cb = (tid >> 7) * 16;
  for (int d0 = 0; d0 < D_N; d0 += 32) {
    __syncthreads();
    {
      const float* fa = &F[(size_t)(t0 + ra) * D_N + d0 + ca];
      float4 a0 = *(const float4*)fa;
      float4 a1 = *(const float4*)(fa + 4);
      As[ca + 0][ra] = a0.x; As[ca + 1][ra] = a0.y; As[ca + 2][ra] = a0.z; As[ca + 3][ra] = a0.w;
      As[ca + 4][ra] = a1.x; As[ca + 5][ra] = a1.y; As[ca + 6][ra] = a1.z; As[ca + 7][ra] = a1.w;
      const float* fb = &C[(size_t)(k0 + rb) * D_N + d0 + cb];
      float4 b0 = *(const float4*)fb;
      float4 b1 = *(const float4*)(fb + 4);
      float4 b2 = *(const float4*)(fb + 8);
      float4 b3 = *(const float4*)(fb + 12);
      Bs[cb + 0][rb] = b0.x; Bs[cb + 1][rb] = b0.y; Bs[cb + 2][rb] = b0.z; Bs[cb + 3][rb] = b0.w;
      Bs[cb + 4][rb] = b1.x; Bs[cb + 5][rb] = b1.y; Bs[cb + 6][rb] = b1.z; Bs[cb + 7][rb] = b1.w;
      Bs[cb + 8][rb] = b2.x; Bs[cb + 9][rb] = b2.y; Bs[cb + 10][rb] = b2.z; Bs[cb + 11][rb] = b2.w;
      Bs[cb + 12][rb] = b3.x; Bs[cb + 13][rb] = b3.y; Bs[cb + 14][rb] = b3.z; Bs[cb + 15][rb] = b3.w;
    }
    __syncthreads();
#pragma unroll
    for (int d = 0; d < 32; ++d) {
      float4 a = *(const float4*)&As[d][ty * 4];
      float4 b0 = *(const float4*)&Bs[d][tx * 4];
      float4 b1 = *(const float4*)&Bs[d][64 + tx * 4];
      float av[4] = {a.x, a.y, a.z, a.w};
      float bv[8] = {b0.x, b0.y, b0.z, b0.w, b1.x, b1.y, b1.z, b1.w};
#pragma unroll
      for (int i = 0; i < 4; ++i)
#pragma unroll
        for (int j = 0; j < 8; ++j)
          acc[i][j] = fmaf(av[i], bv[j], acc[i][j]);
    }
    if (d0 == 352) {
#pragma unroll
      for (int i = 0; i < 4; ++i)
#pragma unroll
        for (int j = 0; j < 8; ++j) { dot[i][j] = acc[i][j]; acc[i][j] = 0.0f; }
    }
    if (d0 == 736) {
#pragma unroll
      for (int i = 0; i < 4; ++i)
#pragma unroll
        for (int j = 0; j < 8; ++j) { dot[i][j] = dot[i][j] + acc[i][j]; acc[i][j] = 0.0f; }
    }
  }
  {
#pragma clang fp contract(off)
#pragma unroll
    for (int i = 0; i < 4; ++i) {
      int t = t0 + ty * 4 + i;
      float sa = sf2[t];
      float o[8];
#pragma unroll
      for (int j = 0; j < 4; ++j) {
        float dsum = dot[i][j] + acc[i][j];
        float two = 2.0f * dsum;
        o[j] = (sa - two) + sc2[k0 + tx * 4 + j];
      }
#pragma unroll
      for (int j = 4; j < 8; ++j) {
        float dsum = dot[i][j] + acc[i][j];
        float two = 2.0f * dsum;
        o[j] = (sa - two) + sc2[k0 + 64 + tx * 4 + (j - 4)];
      }
      float4 o0; o0.x = o[0]; o0.y = o[1]; o0.z = o[2]; o0.w = o[3];
      float4 o1; o1.x = o[4]; o1.y = o[5]; o1.z = o[6]; o1.w = o[7];
      float* dp = &d2[(size_t)t * K_N + k0 + tx * 4];
      *(float4*)dp = o0;
      *(float4*)(dp + 64) = o1;
    }
  }
}

// ---------------- cand: candidate list + dmin + self-sentinel + pack init (no memsets) ------
__global__ __launch_bounds__(256) void k_cand(const float* __restrict__ d2,
                                              int2* __restrict__ cand,
                                              float* __restrict__ dminOut,
                                              unsigned* __restrict__ pack) {
  int wave = threadIdx.x >> 6;
  int lane = threadIdx.x & 63;
  int row = blockIdx.x * 4 + wave;
  const float4* p = (const float4*)(d2 + (size_t)row * K_N + lane * 16);
  float4 v0 = p[0], v1 = p[1], v2 = p[2], v3 = p[3];
  float m = fminf(fminf(fminf(v0.x, v0.y), fminf(v0.z, v0.w)),
                  fminf(fminf(v1.x, v1.y), fminf(v1.z, v1.w)));
  float n = fminf(fminf(fminf(v2.x, v2.y), fminf(v2.z, v2.w)),
                  fminf(fminf(v3.x, v3.y), fminf(v3.z, v3.w)));
  m = fminf(m, n);
  m = fminf(m, __shfl_xor(m, 1, 64));
  m = fminf(m, __shfl_xor(m, 2, 64));
  m = fminf(m, __shfl_xor(m, 4, 64));
  m = fminf(m, __shfl_xor(m, 8, 64));
  m = fminf(m, __shfl_xor(m, 16, 64));
  m = fminf(m, __shfl_xor(m, 32, 64));
  if (lane == 0) {
    dminOut[row] = m;
    pack[row] = 0xFFFFFFFFu;         // fold old hipMemsetAsync(pack) in here
  }
  float thr = m + THR;
  unsigned flags = 0;
#define TESTC(J, VAL) if ((VAL) <= thr) flags |= (1u << (J));
  TESTC(0, v0.x) TESTC(1, v0.y) TESTC(2, v0.z) TESTC(3, v0.w)
  TESTC(4, v1.x) TESTC(5, v1.y) TESTC(6, v1.z) TESTC(7, v1.w)
  TESTC(8, v2.x) TESTC(9, v2.y) TESTC(10, v2.z) TESTC(11, v2.w)
  TESTC(12, v3.x) TESTC(13, v3.y) TESTC(14, v3.z) TESTC(15, v3.w)
#undef TESTC
  int c = __popc(flags);
  int pre = c;
#pragma unroll
  for (int off = 1; off <= 32; off <<= 1) {
    int t = __shfl_up(pre, off, 64);
    if (lane >= off) pre += t;
  }
  int idx = pre - c;
  int total = __builtin_amdgcn_readlane(pre, 63);
  int2* rowp = cand + (size_t)row * CMAX;
  // self-sentinel: slots [total, CMAX) get (-1, NaN) — replaces the cand memset
  if (lane < CMAX && lane >= total) rowp[lane] = make_int2(-1, QNAN);
  int kb = lane * 16;
#define EMITC(J, VAL)                                                        \
  if (flags & (1u << (J))) {                                                 \
    if (idx < CMAX) rowp[idx] = make_int2(kb + (J), __float_as_int(VAL));    \
    ++idx;                                                                   \
  }
  EMITC(0, v0.x) EMITC(1, v0.y) EMITC(2, v0.z) EMITC(3, v0.w)
  EMITC(4, v1.x) EMITC(5, v1.y) EMITC(6, v1.z) EMITC(7, v1.w)
  EMITC(8, v2.x) EMITC(9, v2.y) EMITC(10, v2.z) EMITC(11, v2.w)
  EMITC(12, v3.x) EMITC(13, v3.y) EMITC(14, v3.z) EMITC(15, v3.w)
#undef EMITC
}

// ---------------- prev4: per-group (4 rows x 16 slots) lane statics (r21-validated) ---------
__global__ __launch_bounds__(256) void k_prev4(const int2* __restrict__ cand,
                                               int4* __restrict__ pb1,
                                               int2* __restrict__ pb2) {
  __shared__ int2 rows[4][5][16];   // [wave][4g-1, t0, t1, t2, t3][slot]
  int w = threadIdx.x >> 6, lane = threadIdx.x & 63;
  int g = blockIdx.x * 4 + w;
  int base = 4 * g - 1;
  for (int i = lane; i < 80; i += 64) {
    int rr = i >> 4, ss = i & 15;
    int trow = base + rr;
    rows[w][rr][ss] = (trow >= 0) ? cand[(size_t)trow * CMAX + ss] : make_int2(-2, 0);
  }
  __syncthreads();
  int q = 3 - (lane >> 4);
  int s = lane & 15;
  int2 me = rows[w][1 + q][s];
  int k = me.x;
  int pp = -4, p3s = QNAN;
  int d0s = QNAN, d1s = QNAN, d2s = QNAN;
#pragma unroll
  for (int i = 0; i < 16; ++i) {
    if (rows[w][0][i].x == k) { pp = i * 4; p3s = rows[w][0][i].y; }
    if (rows[w][1][i].x == k) d0s = rows[w][1][i].y;
    if (rows[w][2][i].x == k) d1s = rows[w][2][i].y;
    if (rows[w][3][i].x == k) d2s = rows[w][3][i].y;
  }
  if (k < 0) pp = -4;
  pb1[(size_t)g * 64 + lane] = make_int4(pp, me.y, d0s, d1s);
  pb2[(size_t)g * 64 + lane] = make_int2(d2s, p3s);
}

// ---------------- DPP min within each 16-lane row (result at lanes 15/31/47/63) -------------
__device__ __forceinline__ float dpp_min16(float x) {
  int t;
  t = __builtin_amdgcn_update_dpp(__float_as_int(x), __float_as_int(x), 0x111, 0xF, 0xF, false);
  x = fminf(x, __int_as_float(t));
  t = __builtin_amdgcn_update_dpp(__float_as_int(x), __float_as_int(x), 0x112, 0xF, 0xF, false);
  x = fminf(x, __int_as_float(t));
  t = __builtin_amdgcn_update_dpp(__float_as_int(x), __float_as_int(x), 0x114, 0xF, 0xF, false);
  x = fminf(x, __int_as_float(t));
  t = __builtin_amdgcn_update_dpp(__float_as_int(x), __float_as_int(x), 0x118, 0xF, 0xF, false);
  x = fminf(x, __int_as_float(t));
  return x;
}
__device__ __forceinline__ float rdlane(float x, int l) {
  return __int_as_float(__builtin_amdgcn_readlane(__float_as_int(x), l));
}

// ---------------- pass1: G=4 sparse chain — ONE bpermute per FOUR rows (r21, 509us) ---------
__global__ __launch_bounds__(64, 1) void k_pass1(const int4* __restrict__ pb1,
                                                 const int2* __restrict__ pb2,
                                                 const float* __restrict__ dminArr,
                                                 float* __restrict__ alphaOut) {
  const int lane = threadIdx.x;
  const int q = 3 - (lane >> 4);
  const int4* b1p = pb1 + lane;
  const int2* b2p = pb2 + lane;
  int4 r1[4];
  int2 r2[4];
#pragma unroll
  for (int u = 0; u < 4; ++u) {
    r1[u] = b1p[(size_t)u * 64];
    r2[u] = b2p[(size_t)u * 64];
  }
  float pay = 0.0f;         // group 0: pp=-4, value irrelevant
  float red2c = BIGF;       // -> a_{-2..-1} = 0 at iter 0
  float dm2c = 0.0f, dm3c = 0.0f, a1c = 0.0f;
  float areg = 0.0f;
  const int NG = T_N / 4;
  float dmv = dminArr[lane];
  float dmv_next;
  for (int gb = 0; gb < NG; gb += 16) {
    int nb = gb + 16; if (nb >= NG) nb = 0;
    dmv_next = dminArr[nb * 4 + lane];
    for (int g4 = 0; g4 < 16; g4 += 4) {
#pragma unroll
      for (int u = 0; u < 4; ++u) {
        int g = gb + g4 + u;
        int4 pa = r1[u];
        int2 pb = r2[u];
        // the group's single gather (payload from previous iteration)
        int g1 = __builtin_amdgcn_ds_bpermute(pa.x, __float_as_int(pay));
        // prefetch group g+4
        int gn = g + 4; if (gn > NG - 1) gn = NG - 1;
        r1[u] = b1p[(size_t)gn * 64];
        r2[u] = b2p[(size_t)gn * 64];
        // prologue: finalize a_{4g-2}, a_{4g-1} from carried red2
        float at2p = fminf(rdlane(red2c, 31), dm2c + a1c);
        float ain = fminf(rdlane(red2c, 15), dm3c + at2p);
        int posB = 4 * g - 1;
        if (posB >= 0) {
          areg = (((posB - 1) & 63) == lane) ? at2p : areg;
          areg = ((posB & 63) == lane) ? ain : areg;
          if ((posB & 63) == 63) alphaOut[(posB & ~63) + lane] = areg;
        }
        int r0 = 4 * (g4 + u);
        float dm0 = rdlane(dmv, r0);
        float dm1 = rdlane(dmv, r0 + 1);
        float dm2 = rdlane(dmv, r0 + 2);
        float dm3 = rdlane(dmv, r0 + 3);
        // fp with deferred E-injection
        float injE = __int_as_float(pb.y) + at2p;      // p3s + a_{4g-2}
        float fp = (pa.x < 0) ? BIGF : fminf(__int_as_float(g1), injE);
        // A/B walks (own-row d substituted automatically via self-lookup)
        float dOwn = __int_as_float(pa.y);
        float d0s = __int_as_float(pa.z);
        float d1s = __int_as_float(pa.w);
        float d2s = __int_as_float(pb.x);
        float A0 = d0s + (fp - LMBDA);
        float A1 = d1s + (A0 - LMBDA);
        float A2 = d2s + (A1 - LMBDA);
        float A3 = dOwn + (A2 - LMBDA);
        float B0 = d0s + ain;
        float B1 = d1s + (B0 - LMBDA);
        float B2 = d2s + (B1 - LMBDA);
        float B3 = dOwn + (B2 - LMBDA);
        float xA = (q == 0) ? A0 : (q == 1) ? A1 : (q == 2) ? A2 : A3;
        float xB = (q == 0) ? B0 : (q == 1) ? B1 : (q == 2) ? B2 : B3;
        float xAB = fminf(xA, xB);
        float red1 = dpp_min16(xAB);
        float a0 = rdlane(red1, 63);                   // a_t0 (A,B complete for t0)
        float a1 = fminf(rdlane(red1, 47), dm1 + a0);  // a_t1 (+C via dmin)
        areg = (((4 * g) & 63) == lane) ? a0 : areg;       // pos % 4 == 0: never flushes
        areg = (((4 * g + 1) & 63) == lane) ? a1 : areg;   // pos % 4 == 1: never flushes
        // C/D folds for rows t2, t3
        float cw1 = d1s + a0;
        float cw2 = d2s + (cw1 - LMBDA);
        float Cin = (q == 2) ? cw1 : cw2;
        float Cterm = dOwn + (Cin - LMBDA);
        float Dterm = dOwn + ((d2s + a1) - LMBDA);
        Dterm = (q == 3) ? Dterm : __int_as_float(QNAN);
        float xr = fminf(fminf(xAB, Cterm), Dterm);
        float red2 = dpp_min16(xr);
        // carries
        pay = xr;                // Q3 lanes hold the t3-slot payload
        red2c = red2;
        dm2c = dm2; dm3c = dm3; a1c = a1;
      }
    }
    dmv = dmv_next;
  }
  // epilogue: a_{8190}, a_{8191}
  float at2 = fminf(rdlane(red2c, 31), dm2c + a1c);
  float at3 = fminf(rdlane(red2c, 15), dm3c + at2);
  areg = ((8190 & 63) == lane) ? at2 : areg;
  areg = ((8191 & 63) == lane) ? at3 : areg;
  alphaOut[(T_N - 64) + lane] = areg;
}

// ---------------- pass2: chunked warm-start replay per k (WARM=64 validated; CH=128) --------
#define CH 128
#define WARM 64
__global__ __launch_bounds__(256) void k_pass2(const float* __restrict__ d2,
                                               const float* __restrict__ AOUT,
                                               unsigned* __restrict__ pack) {
  int kb = blockIdx.x & 3;
  int tc = blockIdx.x >> 2;
  int k = kb * 256 + threadIdx.x;
  int ts = tc * CH;
  int start = ts - WARM; if (start < 0) start = 0;
  int end = ts + CH;
  __shared__ float lal[CH + WARM + 1];
  for (int i = threadIdx.x; i < end - start + 1; i += 256) {
    int idx = start - 1 + i;
    lal[i] = (idx < 0) ? 0.0f : AOUT[idx];
  }
  __syncthreads();
  float f = BIGF;
  unsigned s = 0;
#pragma unroll 4
  for (int tau = start; tau < end; ++tau) {
    float a_in = lal[tau - start];
    float d = d2[(size_t)tau * K_N + k];
    float ext = f - LMBDA;
    if (a_in < ext) s = (unsigned)tau;
    f = d + fminf(a_in, ext);
    if (tau >= ts) {
      float a_out = lal[tau - start + 1];
      if (f == a_out) atomicMin(&pack[tau], ((unsigned)k << 13) | s);
    }
  }
}

// ---------------- backtrack: ballot run-skip serial chase + parallel fill (validated r1) ----------------
__global__ __launch_bounds__(256) void k_backtrack(const unsigned* __restrict__ pack,
                                                   unsigned* __restrict__ unitsWs,
                                                   float* __restrict__ outUnits) {
  __shared__ unsigned lp[T_N];
  __shared__ unsigned long long msk[T_N / 64];
  int tid = threadIdx.x;
  for (int i = tid * 4; i < T_N; i += 1024) {
    *(uint4*)&lp[i] = *(const uint4*)&pack[i];
  }
  __syncthreads();
  if (tid < 64) {
    int lane = tid;
    int cur = T_N;
    for (int B = T_N - 64; B >= 0; B -= 64) {
      unsigned long long marks = 0ull;
      if (cur > B) {
        unsigned pk = lp[B + lane];
        int bv = (int)(pk & 8191u);
        unsigned long long run = __ballot(bv == B + lane);
        while (cur > B) {
          int L = cur - 1 - B;
          unsigned long long below = (L == 63) ? ~0ull : ((1ull << (L + 1)) - 1ull);
          unsigned long long nz = (~run) & below;
          if (nz == 0ull) { marks |= below; cur = B; break; }
          int j = 63 - __builtin_clzll(nz);
          marks |= below & ~((1ull << j) - 1ull);
          int nb = __builtin_amdgcn_readlane(bv, j);
          cur = nb;
          if (cur > B + j) cur = B + j;
        }
      }
      if (lane == 0) msk[B >> 6] = marks;
    }
  }
  __syncthreads();
  for (int p = tid; p < T_N; p += 256) {
    int w = p >> 6;
    unsigned long long m = msk[w] & (~0ull << (p & 63));
    while (m == 0ull) { ++w; m = msk[w]; }
    int idx = (w << 6) + (int)__builtin_ctzll(m);
    unsigned g = (lp[idx] >> 13) & 1023u;
    unitsWs[p] = g;
    outUnits[p] = (float)g;
  }
}

// ---------------- gather: quantized[t] = codebook[units[t]] ----------------
__global__ __launch_bounds__(256) void k_gather(const float* __restrict__ C,
                                                const unsigned* __restrict__ unitsWs,
                                                float* __restrict__ out) {
  int t = blockIdx.x;
  unsigned u = unitsWs[t] & 1023u;
  const float4* src = (const float4*)(C + (size_t)u * D_N);
  float4* dst = (float4*)(out + (size_t)t * D_N);
  dst[threadIdx.x] = src[threadIdx.x];
}

extern "C" void kernel_launch(void* const* d_in, const int* in_sizes, int n_in,
                              void* d_out, int out_size, void* d_ws, size_t ws_size,
                              hipStream_t stream) {
  const float* F = (const float*)d_in[0];
  const float* C = (const float*)d_in[1];
  float* out = (float*)d_out;
  float* d2 = out;                                  // reuse quantized region as d2 scratch
  float* outUnits = out + (size_t)T_N * D_N;
  char* ws = (char*)d_ws;
  float* alphaOut = (float*)(ws);                    // 32 KB
  unsigned* pack = (unsigned*)(ws + (32 << 10));     // 32 KB
  unsigned* unitsWs = (unsigned*)(ws + (64 << 10));  // 32 KB
  float* sf2 = (float*)(ws + (96 << 10));            // 32 KB
  float* sc2 = (float*)(ws + (128 << 10));           // 4 KB
  float* dminArr = (float*)(ws + (160 << 10));       // 32 KB
  int2* cand = (int2*)(ws + (1 << 20));              // 1 MB (8192 x 16 x 8B)
  int4* pb1 = (int4*)(ws + (3 << 20));               // 2 MB (2048 x 64 x 16B)
  int2* pb2 = (int2*)(ws + (5 << 20));               // 1 MB (2048 x 64 x 8B)

  k_norms<<<(T_N + K_N) / 4, 256, 0, stream>>>(F, C, sf2, sc2);
  k_gemm<<<(T_N / 64) * (K_N / 128), 256, 0, stream>>>(F, C, sf2, sc2, d2);
  k_cand<<<T_N / 4, 256, 0, stream>>>(d2, cand, dminArr, pack);
  k_prev4<<<(T_N / 4) / 4, 256, 0, stream>>>(cand, pb1, pb2);
  k_pass1<<<1, 64, 0, stream>>>(pb1, pb2, dminArr, alphaOut);
  k_pass2<<<(T_N / CH) * 4, 256, 0, stream>>>(d2, alphaOut, pack);
  k_backtrack<<<1, 256, 0, stream>>>(pack, unitsWs, outUnits);
  k_gather<<<T_N, 256, 0, stream>>>(C, unitsWs, out);
}